// Round 4
// baseline (91.625 us; speedup 1.0000x reference)
//
#include <hip/hip_runtime.h>
#include <math.h>

// CapsuleLayer dynamic routing, MI355X.
// B=128, R=4096, IN=16, OUT=32, C=2, 3 routing iterations.
// K1 priors GEMM (+ fp16 s0 partials) -> red0 (v0) ->
// pass(v0) -> redv (vsum=v0+v1) -> pass(vsum) -> redv (out).
// Logits never stored: L_k = p . Vsum_k (linear in the running v sum).
#define CB   128
#define CR   4096
#define CIN  16
#define COUT 32
#define CCAP 2
#define RT2  8           // r rows per kernel1 block (16 KB W tile in LDS)
#define NCH  8           // r-chunks per (c,b) in pass kernels
#define EPSF 1e-12f

typedef _Float16 h8  __attribute__((ext_vector_type(8)));
typedef float    f8v __attribute__((ext_vector_type(8)));

// ---------------------------------------------------------------------------
// Kernel 1: priors[c][b][r][o] = sum_i x[b][r][i] * W[c][r][i][o]  (fp16 out)
// plus per-block s0 partials, fp16: s0p[c][rt][b][o].
// grid = C*512 blocks (c, 8-row r-tile), 256 threads (b = t>>1, og = t&1).
// W tile staged to LDS ONCE per block (one barrier), then a barrier-free
// 8-row loop: x global loads + LDS-broadcast W reads. 4 blocks/CU for TLP.
// R3 lesson: the old 1024-thread 1-block/CU version with a barrier per
// 4-row W stage was latency-bound at 45us (all waves stall on the sync).
// ---------------------------------------------------------------------------
__global__ __launch_bounds__(256) void caps_priors_kernel(
    const float* __restrict__ x, const float* __restrict__ w,
    _Float16* __restrict__ priors, _Float16* __restrict__ s0p)
{
  const int c  = (int)(blockIdx.x >> 9);
  const int rt = (int)(blockIdx.x & 511);
  const int r0 = rt * RT2;
  const int t  = (int)threadIdx.x;
  const int b  = t >> 1;        // 0..127
  const int og = t & 1;
  const int o0 = og * 16;

  __shared__ __align__(16) float Wl[RT2 * CIN * COUT];   // 16 KB

  {
    // 8 contiguous W rows = 4096 floats; 256 threads x 4 float4, coalesced.
    const float4* wp = (const float4*)(w + ((size_t)c * CR + r0) * (CIN * COUT));
    float4* wl = (float4*)Wl;
#pragma unroll
    for (int j = 0; j < 4; ++j) wl[t + j * 256] = wp[t + j * 256];
  }
  __syncthreads();

  float s0a[16];
#pragma unroll
  for (int j = 0; j < 16; ++j) s0a[j] = 0.f;

#pragma unroll
  for (int rr = 0; rr < RT2; ++rr) {
    const int r = r0 + rr;
    const float4* xp = (const float4*)(x + ((size_t)b * CR + r) * CIN);
    float4 x0 = xp[0], x1 = xp[1], x2 = xp[2], x3 = xp[3];
    float xs[16] = {x0.x, x0.y, x0.z, x0.w, x1.x, x1.y, x1.z, x1.w,
                    x2.x, x2.y, x2.z, x2.w, x3.x, x3.y, x3.z, x3.w};

    float p[16];
#pragma unroll
    for (int j = 0; j < 16; ++j) p[j] = 0.f;

    const float* wrow = &Wl[rr * (CIN * COUT) + o0];
#pragma unroll
    for (int i = 0; i < 16; ++i) {
      const float4* wl4 = (const float4*)(wrow + i * COUT);
      float4 w0 = wl4[0], w1 = wl4[1], w2 = wl4[2], w3 = wl4[3];
      const float xi = xs[i];
      p[0]  += xi * w0.x;  p[1]  += xi * w0.y;  p[2]  += xi * w0.z;  p[3]  += xi * w0.w;
      p[4]  += xi * w1.x;  p[5]  += xi * w1.y;  p[6]  += xi * w1.z;  p[7]  += xi * w1.w;
      p[8]  += xi * w2.x;  p[9]  += xi * w2.y;  p[10] += xi * w2.z;  p[11] += xi * w2.w;
      p[12] += xi * w3.x;  p[13] += xi * w3.y;  p[14] += xi * w3.z;  p[15] += xi * w3.w;
    }

    h8 ha, hb;
#pragma unroll
    for (int j = 0; j < 8; ++j) { ha[j] = (_Float16)p[j]; hb[j] = (_Float16)p[j + 8]; }
#pragma unroll
    for (int j = 0; j < 16; ++j) s0a[j] += p[j];

    _Float16* pr = priors + (((size_t)(c * CB + b)) * CR + r) * COUT + o0;
    ((h8*)pr)[0] = ha;
    ((h8*)pr)[1] = hb;
  }

  // fp16-packed partial store (one per block-row-tile): s0p[c][rt][b][o]
  h8 sa, sb;
#pragma unroll
  for (int j = 0; j < 8; ++j) { sa[j] = (_Float16)s0a[j]; sb[j] = (_Float16)s0a[j + 8]; }
  _Float16* sp = s0p + (((size_t)c * 512 + rt) * CB + b) * COUT + o0;
  ((h8*)sp)[0] = sa;
  ((h8*)sp)[1] = sb;
}

// ---------------------------------------------------------------------------
// red0: v0 = squash(mean_r priors) from fp16 s0p. grid 256 (c,b) x 256 thr.
// thread t: og8 = t&3 (8-wide o group), g = t>>2 (0..63); h8 vector loads.
// ---------------------------------------------------------------------------
__global__ __launch_bounds__(256) void caps_red0_kernel(
    const _Float16* __restrict__ s0p, float* __restrict__ vsum)
{
  const int cb  = (int)blockIdx.x;
  const int c   = cb >> 7, b = cb & 127;
  const int t   = (int)threadIdx.x;
  const int og8 = t & 3, g = t >> 2;

  float a8[8];
#pragma unroll
  for (int k = 0; k < 8; ++k) a8[k] = 0.f;

#pragma unroll
  for (int jj = 0; jj < 8; ++jj) {
    const int j = g + jj * 64;
    h8 v = *(const h8*)(s0p + (((size_t)c * 512 + j) * CB + b) * COUT + og8 * 8);
    f8v f = __builtin_convertvector(v, f8v);
#pragma unroll
    for (int k = 0; k < 8; ++k) a8[k] += f[k];
  }

  __shared__ float R[64][33];
#pragma unroll
  for (int k = 0; k < 8; ++k) R[g][og8 * 8 + k] = a8[k];
  __syncthreads();

  if (t < 32) {
    float s0 = 0.f;
#pragma unroll 8
    for (int gg = 0; gg < 64; ++gg) s0 += R[gg][t];
    float sm = s0 * (1.f / (float)CR);
    float sn = sm * sm;
#pragma unroll
    for (int sh = 1; sh < 32; sh <<= 1) sn += __shfl_xor(sn, sh);
    float fac = sn / ((1.f + sn + EPSF) * sqrtf(sn + EPSF));
    vsum[cb * COUT + t] = sm * fac;
  }
}

// ---------------------------------------------------------------------------
// pass: for each row r of (c,b): e = exp(p . vsum); partial s = sum e*p, esum.
// grid = 256*NCH blocks, 256 threads, 2 rows/thread. partial[cb][ch][33]
// ---------------------------------------------------------------------------
__global__ __launch_bounds__(256) void caps_pass_kernel(
    const _Float16* __restrict__ priors, const float* __restrict__ vsum,
    float* __restrict__ partial)
{
  const int bid = (int)blockIdx.x;
  const int cb  = bid >> 3, ch = bid & (NCH - 1);
  const int t   = (int)threadIdx.x;
  const int wid = t >> 6, lane = t & 63;

  __shared__ __align__(16) float vl[32];
  __shared__ float rl[4][33];

  if (t < 32) vl[t] = vsum[cb * COUT + t];
  __syncthreads();

  float v[32];
#pragma unroll
  for (int k = 0; k < 8; ++k) {
    float4 vv = ((const float4*)vl)[k];
    v[4 * k] = vv.x; v[4 * k + 1] = vv.y; v[4 * k + 2] = vv.z; v[4 * k + 3] = vv.w;
  }

  float acc[32];
#pragma unroll
  for (int k = 0; k < 32; ++k) acc[k] = 0.f;
  float esum = 0.f;

#pragma unroll
  for (int q = 0; q < 2; ++q) {
    const int r = ch * 512 + q * 256 + t;
    const h8* pr = (const h8*)(priors + (((size_t)cb) * CR + r) * COUT);
    h8 a0 = pr[0], a1 = pr[1], a2 = pr[2], a3 = pr[3];
    f8v f0 = __builtin_convertvector(a0, f8v);
    f8v f1 = __builtin_convertvector(a1, f8v);
    f8v f2 = __builtin_convertvector(a2, f8v);
    f8v f3 = __builtin_convertvector(a3, f8v);

    float d = 0.f;
#pragma unroll
    for (int k = 0; k < 8; ++k)
      d += f0[k] * v[k] + f1[k] * v[k + 8] + f2[k] * v[k + 16] + f3[k] * v[k + 24];

    const float e = __expf(d);   // safe: |d| <= ||p_row|| * ||vsum|| < ~80
    esum += e;
#pragma unroll
    for (int k = 0; k < 8; ++k) {
      acc[k]      += e * f0[k];
      acc[k + 8]  += e * f1[k];
      acc[k + 16] += e * f2[k];
      acc[k + 24] += e * f3[k];
    }
  }

  // wave reduce then cross-wave via LDS
#pragma unroll
  for (int sh = 1; sh < 64; sh <<= 1) {
#pragma unroll
    for (int k = 0; k < 32; ++k) acc[k] += __shfl_xor(acc[k], sh);
    esum += __shfl_xor(esum, sh);
  }
  if (lane == 0) {
#pragma unroll
    for (int k = 0; k < 32; ++k) rl[wid][k] = acc[k];
    rl[wid][32] = esum;
  }
  __syncthreads();
  if (t < 33) {
    float s = rl[0][t] + rl[1][t] + rl[2][t] + rl[3][t];
    partial[(size_t)bid * 33 + t] = s;
  }
}

// ---------------------------------------------------------------------------
// redv: reduce partials -> v = squash(s/esum); vsum += v, or write out (final).
// grid 256 (c,b) x 64 threads.
// ---------------------------------------------------------------------------
__global__ __launch_bounds__(64) void caps_redv_kernel(
    const float* __restrict__ partial, float* __restrict__ vsum,
    float* __restrict__ out, int final_)
{
  const int cb = (int)blockIdx.x;
  const int t  = (int)threadIdx.x;
  __shared__ float sf[33];
  if (t < 33) {
    float s = 0.f;
#pragma unroll
    for (int j = 0; j < NCH; ++j) s += partial[((size_t)cb * NCH + j) * 33 + t];
    sf[t] = s;
  }
  __syncthreads();
  if (t < 32) {
    float inv = 1.f / sf[32];
    float sm = sf[t] * inv;
    float sn = sm * sm;
#pragma unroll
    for (int sh = 1; sh < 32; sh <<= 1) sn += __shfl_xor(sn, sh);
    float fac = sn / ((1.f + sn + EPSF) * sqrtf(sn + EPSF));
    float vv = sm * fac;
    if (final_) out[cb * COUT + t] = vv;
    else        vsum[cb * COUT + t] += vv;
  }
}

extern "C" void kernel_launch(void* const* d_in, const int* in_sizes, int n_in,
                              void* d_out, int out_size, void* d_ws, size_t ws_size,
                              hipStream_t stream) {
  const float* x = (const float*)d_in[0];
  const float* w = (const float*)d_in[1];
  float* out = (float*)d_out;

  char* p = (char*)d_ws;
  _Float16* priors = (_Float16*)p;                 // 67,108,864 B
  p += (size_t)CCAP * CB * CR * COUT * sizeof(_Float16);
  _Float16* s0p = (_Float16*)p;                    // 8,388,608 B (fp16)
  p += (size_t)CCAP * 512 * CB * COUT * sizeof(_Float16);
  float* vsum = (float*)p;                         // 32,768 B
  p += (size_t)CCAP * CB * COUT * sizeof(float);
  float* partial = (float*)p;                      // 270,336 B
  // total 75,800,576 B

  caps_priors_kernel<<<dim3(CCAP * 512), 256, 0, stream>>>(x, w, priors, s0p);
  caps_red0_kernel<<<dim3(CCAP * CB), 256, 0, stream>>>(s0p, vsum);
  caps_pass_kernel<<<dim3(CCAP * CB * NCH), 256, 0, stream>>>(priors, vsum, partial);
  caps_redv_kernel<<<dim3(CCAP * CB), 64, 0, stream>>>(partial, vsum, out, 0);
  caps_pass_kernel<<<dim3(CCAP * CB * NCH), 256, 0, stream>>>(priors, vsum, partial);
  caps_redv_kernel<<<dim3(CCAP * CB), 64, 0, stream>>>(partial, vsum, out, 1);
}